// Round 8
// baseline (362.835 us; speedup 1.0000x reference)
//
#include <hip/hip_runtime.h>
#include <math.h>

#define D_MODEL 512
#define BATCH 8
#define SEQ 512
#define HEAD 64
#define DK 4
#define DV 8
#define HIDD 10

// proj tiled-GEMM params (r5-proven best: 120 us measured; FROZEN)
#define MR 32
#define KC 32
#define NC 256

__device__ __forceinline__ float4 fma4(float s, float4 w, float4 a) {
    a.x = fmaf(s, w.x, a.x); a.y = fmaf(s, w.y, a.y);
    a.z = fmaf(s, w.z, a.z); a.w = fmaf(s, w.w, a.w);
    return a;
}

// ---------------------------------------------------------------------------
// proj (r5-proven, FROZEN): self Q/K/V from x + cross K/V from x_enc in one
// launch. 7 col-jobs x 128 row-blocks = 896 blocks. Outputs head-major.
// ---------------------------------------------------------------------------
__global__ __launch_bounds__(256) void proj_kernel(
    const float* __restrict__ x, const float* __restrict__ xe,
    const float* __restrict__ Wq, const float* __restrict__ Wk,
    const float* __restrict__ Wv,
    float* __restrict__ Q2, float* __restrict__ K2, float* __restrict__ V2,
    float* __restrict__ Kc, float* __restrict__ Vc)
{
    __shared__ float xt[KC * MR];   // [k][r]  4 KB
    __shared__ float wt[KC * NC];   // [k][c] 32 KB

    const int t  = threadIdx.x;
    const int bj = blockIdx.x >> 7;      // 0..6 col-job
    const int br = blockIdx.x & 127;     // row block
    const int r0 = br * MR;

    const float* X; const float* W; int ldw; int c0; float* dst; int vt;
    switch (bj) {
      case 0:  X = x;  W = Wq; ldw = 256; c0 = 0;   dst = Q2; vt = 0; break;
      case 1:  X = x;  W = Wk; ldw = 256; c0 = 0;   dst = K2; vt = 0; break;
      case 2:  X = x;  W = Wv; ldw = 512; c0 = 0;   dst = V2; vt = 1; break;
      case 3:  X = x;  W = Wv; ldw = 512; c0 = 256; dst = V2; vt = 1; break;
      case 4:  X = xe; W = Wk; ldw = 256; c0 = 0;   dst = Kc; vt = 0; break;
      case 5:  X = xe; W = Wv; ldw = 512; c0 = 0;   dst = Vc; vt = 1; break;
      default: X = xe; W = Wv; ldw = 512; c0 = 256; dst = Vc; vt = 1; break;
    }

    const int rg = t >> 6;
    const int cq = t & 63;
    const int rs = t & 31;
    const int kq = t >> 5;

    float4 acc[8];
#pragma unroll
    for (int r = 0; r < 8; ++r) acc[r] = make_float4(0.f, 0.f, 0.f, 0.f);

    for (int kc = 0; kc < D_MODEL; kc += KC) {
        const float4 xa = *(const float4*)(X + (long)(r0 + rs) * D_MODEL + kc + kq * 4);
        xt[(kq * 4 + 0) * MR + rs] = xa.x;
        xt[(kq * 4 + 1) * MR + rs] = xa.y;
        xt[(kq * 4 + 2) * MR + rs] = xa.z;
        xt[(kq * 4 + 3) * MR + rs] = xa.w;

#pragma unroll
        for (int i = 0; i < 8; ++i) {
            const int row = i * 4 + rg;
            *(float4*)(wt + row * NC + cq * 4) =
                *(const float4*)(W + (long)(kc + row) * ldw + c0 + cq * 4);
        }
        __syncthreads();

#pragma unroll 4
        for (int k = 0; k < KC; ++k) {
            const float4 w4 = *(const float4*)(wt + k * NC + cq * 4);
            const float4 x0 = *(const float4*)(xt + k * MR + rg * 8);
            const float4 x1 = *(const float4*)(xt + k * MR + rg * 8 + 4);
            acc[0] = fma4(x0.x, w4, acc[0]);
            acc[1] = fma4(x0.y, w4, acc[1]);
            acc[2] = fma4(x0.z, w4, acc[2]);
            acc[3] = fma4(x0.w, w4, acc[3]);
            acc[4] = fma4(x1.x, w4, acc[4]);
            acc[5] = fma4(x1.y, w4, acc[5]);
            acc[6] = fma4(x1.z, w4, acc[6]);
            acc[7] = fma4(x1.w, w4, acc[7]);
        }
        __syncthreads();
    }

    const int b = r0 >> 9;
    const int sb = (r0 & 511) + rg * 8;
    if (vt == 0) {
#pragma unroll
        for (int r = 0; r < 8; ++r)
            *(float4*)(dst + (((long)b * HEAD + cq) * SEQ + sb + r) * 4) = acc[r];
    } else {
        const int col = c0 + cq * 4;
        const int h = col >> 3;
        const int off = col & 7;
#pragma unroll
        for (int r = 0; r < 8; ++r)
            *(float4*)(dst + (((long)b * HEAD + h) * SEQ + sb + r) * 8 + off) = acc[r];
    }
}

// ---------------------------------------------------------------------------
// proj2 (r5-proven, FROZEN): Q only, split-K x2 (Qa + Qb; attn sums on load).
// ---------------------------------------------------------------------------
__global__ __launch_bounds__(256, 8) void proj2_kernel(
    const float* __restrict__ A, const float* __restrict__ Wq,
    float* __restrict__ Qa, float* __restrict__ Qb)
{
    __shared__ float xt[32 * 32];   // 4 KB
    __shared__ float wt[32 * 64];   // 8 KB

    const int t  = threadIdx.x;
    const int kh = blockIdx.x & 1;
    const int bj = (blockIdx.x >> 1) & 3;
    const int br = blockIdx.x >> 3;
    const int r0 = br * 32;
    const int c0 = bj * 64;
    const int kb = kh * 256;
    float* dst = kh ? Qb : Qa;

    const int cq = t & 15;
    const int rr = t >> 4;
    const int rs = t & 31, kq = t >> 5;

    float4 acc[2];
    acc[0] = make_float4(0.f, 0.f, 0.f, 0.f);
    acc[1] = acc[0];

    for (int kc = 0; kc < 256; kc += 32) {
        const float4 xa = *(const float4*)(A + (long)(r0 + rs) * D_MODEL + kb + kc + kq * 4);
        xt[(kq * 4 + 0) * 32 + rs] = xa.x;
        xt[(kq * 4 + 1) * 32 + rs] = xa.y;
        xt[(kq * 4 + 2) * 32 + rs] = xa.z;
        xt[(kq * 4 + 3) * 32 + rs] = xa.w;
#pragma unroll
        for (int i = 0; i < 2; ++i) {
            const int row = i * 16 + (t >> 4);
            *(float4*)(wt + row * 64 + (t & 15) * 4) =
                *(const float4*)(Wq + (long)(kb + kc + row) * 256 + c0 + (t & 15) * 4);
        }
        __syncthreads();
#pragma unroll 4
        for (int k = 0; k < 32; ++k) {
            const float4 w4 = *(const float4*)(wt + k * 64 + cq * 4);
            const float2 x2 = *(const float2*)(xt + k * 32 + rr * 2);
            acc[0] = fma4(x2.x, w4, acc[0]);
            acc[1] = fma4(x2.y, w4, acc[1]);
        }
        __syncthreads();
    }

    const int b  = r0 >> 9;
    const int sb = (r0 & 511) + rr * 2;
    const int h  = (c0 >> 2) + cq;
#pragma unroll
    for (int r = 0; r < 2; ++r)
        *(float4*)(dst + (((long)b * HEAD + h) * SEQ + sb + r) * 4) = acc[r];
}

// ---------------------------------------------------------------------------
// Attention v3: 4 queries/thread + split-K x2. Block = (bh, khalf), 128
// threads (2 waves), grid 1024 -> 4 blocks/CU, 8 waves/CU. Per-CU LDS
// broadcast insts drop 4x vs r0 (6144 x ~7.4cyc = 19us < VALU ~26us ->
// VALU-bound). Inline multiplicative mask (masked scores EXACTLY 0,
// participate — refcheck-proven r2/r4). Causal kh=1 wave 0 is fully masked
// -> wave-uniform shortcut (m=0, l=256, a=colsum V). Unnormalized partials.
// ---------------------------------------------------------------------------
template <int CAUSAL>
__device__ __forceinline__ void scan4(
    const float* __restrict__ Kl, const float* __restrict__ Vl,
    const float4 (&qv)[4], const int (&qb)[4],
    float (&m)[4], float (&l)[4], float (&A)[4][8])
{
    for (int s0 = 0; s0 < 256; s0 += 4) {
        float4 k[4];
#pragma unroll
        for (int i = 0; i < 4; ++i)
            k[i] = *(const float4*)(Kl + (s0 + i) * DK);
        float sc[4][4];
#pragma unroll
        for (int j = 0; j < 4; ++j) {
#pragma unroll
            for (int i = 0; i < 4; ++i) {
                const float d = fmaf(qv[j].x, k[i].x, fmaf(qv[j].y, k[i].y,
                                fmaf(qv[j].z, k[i].z, qv[j].w * k[i].w)));
                sc[j][i] = (CAUSAL && (s0 + i) > qb[j]) ? 0.f : d;
            }
            const float gm = fmaxf(fmaxf(sc[j][0], sc[j][1]),
                                   fmaxf(sc[j][2], sc[j][3]));
            if (gm > m[j]) {
                const float s = __builtin_amdgcn_exp2f(m[j] - gm); // exp2(-inf)=0
                l[j] *= s;
#pragma unroll
                for (int r = 0; r < 8; ++r) A[j][r] *= s;
                m[j] = gm;
            }
        }
#pragma unroll
        for (int i = 0; i < 4; ++i) {
            const float4 v0 = *(const float4*)(Vl + (s0 + i) * DV);
            const float4 v1 = *(const float4*)(Vl + (s0 + i) * DV + 4);
#pragma unroll
            for (int j = 0; j < 4; ++j) {
                const float p = __builtin_amdgcn_exp2f(sc[j][i] - m[j]);
                l[j] += p;
                A[j][0] = fmaf(p, v0.x, A[j][0]); A[j][1] = fmaf(p, v0.y, A[j][1]);
                A[j][2] = fmaf(p, v0.z, A[j][2]); A[j][3] = fmaf(p, v0.w, A[j][3]);
                A[j][4] = fmaf(p, v1.x, A[j][4]); A[j][5] = fmaf(p, v1.y, A[j][5]);
                A[j][6] = fmaf(p, v1.z, A[j][6]); A[j][7] = fmaf(p, v1.w, A[j][7]);
            }
        }
    }
}

__global__ __launch_bounds__(128) void attn_kernel(
    const float* __restrict__ Qa, const float* __restrict__ Qb,
    const float* __restrict__ K2, const float* __restrict__ V2,
    float* __restrict__ PA, float* __restrict__ PM, const int causal)
{
    __shared__ float Kl[256 * DK];   // 4 KB
    __shared__ float Vl[256 * DV];   // 8 KB

    const int t  = threadIdx.x;      // 0..127
    const int bh = blockIdx.x >> 1;
    const int kh = blockIdx.x & 1;

    const float4* Ks = (const float4*)(K2 + ((long)bh * SEQ + kh * 256) * DK);
    ((float4*)Kl)[t]       = Ks[t];
    ((float4*)Kl)[t + 128] = Ks[t + 128];
    const float4* Vs = (const float4*)(V2 + ((long)bh * SEQ + kh * 256) * DV);
#pragma unroll
    for (int i = 0; i < 4; ++i)
        ((float4*)Vl)[t + i * 128] = Vs[t + i * 128];
    __syncthreads();

    const long pbase = ((long)(bh * 2 + kh)) * SEQ + t * 4;

    if (causal && kh == 1 && t < 64) {
        // wave 0: queries 4t..4t+3 < 256, all keys 256..511 masked -> all
        // scores exactly 0 -> partial (m=0, l=256, a = column-sum of V).
        float s[8] = {0.f, 0.f, 0.f, 0.f, 0.f, 0.f, 0.f, 0.f};
#pragma unroll
        for (int i = 0; i < 4; ++i) {
            const float4 v0 = *(const float4*)(Vl + (t + i * 64) * DV);
            const float4 v1 = *(const float4*)(Vl + (t + i * 64) * DV + 4);
            s[0] += v0.x; s[1] += v0.y; s[2] += v0.z; s[3] += v0.w;
            s[4] += v1.x; s[5] += v1.y; s[6] += v1.z; s[7] += v1.w;
        }
#pragma unroll
        for (int o = 32; o > 0; o >>= 1)
#pragma unroll
            for (int j = 0; j < 8; ++j) s[j] += __shfl_xor(s[j], o);
#pragma unroll
        for (int j = 0; j < 4; ++j) {
            *(float4*)(PA + (pbase + j) * 8)     = make_float4(s[0], s[1], s[2], s[3]);
            *(float4*)(PA + (pbase + j) * 8 + 4) = make_float4(s[4], s[5], s[6], s[7]);
            *(float2*)(PM + (pbase + j) * 2)     = make_float2(0.f, 256.f);
        }
        return;
    }

    const float cf = 0.5f * 1.44269504088896340736f;  // 1/sqrt(DK) * log2(e)
    float4 qv[4]; int qb[4];
#pragma unroll
    for (int j = 0; j < 4; ++j) {
        const int q = t * 4 + j;
        float4 v = *(const float4*)(Qa + ((long)bh * SEQ + q) * 4);
        if (Qb) {
            const float4 w = *(const float4*)(Qb + ((long)bh * SEQ + q) * 4);
            v.x += w.x; v.y += w.y; v.z += w.z; v.w += w.w;
        }
        v.x *= cf; v.y *= cf; v.z *= cf; v.w *= cf;
        qv[j] = v;
        qb[j] = q - kh * 256;
    }

    float m[4], l[4], A[4][8];
#pragma unroll
    for (int j = 0; j < 4; ++j) {
        m[j] = -INFINITY; l[j] = 0.f;
#pragma unroll
        for (int r = 0; r < 8; ++r) A[j][r] = 0.f;
    }

    if (causal) scan4<1>(Kl, Vl, qv, qb, m, l, A);
    else        scan4<0>(Kl, Vl, qv, qb, m, l, A);

#pragma unroll
    for (int j = 0; j < 4; ++j) {
        *(float4*)(PA + (pbase + j) * 8)     = make_float4(A[j][0], A[j][1], A[j][2], A[j][3]);
        *(float4*)(PA + (pbase + j) * 8 + 4) = make_float4(A[j][4], A[j][5], A[j][6], A[j][7]);
        *(float2*)(PM + (pbase + j) * 2)     = make_float2(m[j], l[j]);
    }
}

// ---------------------------------------------------------------------------
// Combine the two K-half partials of stage 1 -> row-major A [b][s][512]
// (r2-refcheck-proven).
// ---------------------------------------------------------------------------
__global__ __launch_bounds__(256) void combine_kernel(
    const float* __restrict__ PA, const float* __restrict__ PM,
    float* __restrict__ A)
{
    const int tid = blockIdx.x * 256 + threadIdx.x;   // 0..262143
    const int bh  = tid >> 9;
    const int q   = tid & 511;
    const long p0 = ((long)bh * 2 + 0) * SEQ + q;
    const long p1 = ((long)bh * 2 + 1) * SEQ + q;
    const float2 ml0 = *(const float2*)(PM + p0 * 2);
    const float2 ml1 = *(const float2*)(PM + p1 * 2);
    const float M = fmaxf(ml0.x, ml1.x);
    float w0 = __builtin_amdgcn_exp2f(ml0.x - M);
    float w1 = __builtin_amdgcn_exp2f(ml1.x - M);
    const float inv = 1.0f / fmaf(ml0.y, w0, ml1.y * w1);
    w0 *= inv; w1 *= inv;
    const float4 x0 = *(const float4*)(PA + p0 * 8);
    const float4 x1 = *(const float4*)(PA + p0 * 8 + 4);
    const float4 y0 = *(const float4*)(PA + p1 * 8);
    const float4 y1 = *(const float4*)(PA + p1 * 8 + 4);
    const int b = bh >> 6, h = bh & 63;
    float* dst = A + ((long)b * SEQ + q) * D_MODEL + h * DV;
    *(float4*)(dst)     = make_float4(x0.x*w0 + y0.x*w1, x0.y*w0 + y0.y*w1,
                                      x0.z*w0 + y0.z*w1, x0.w*w0 + y0.w*w1);
    *(float4*)(dst + 4) = make_float4(x1.x*w0 + y1.x*w1, x1.y*w0 + y1.y*w1,
                                      x1.z*w0 + y1.z*w1, x1.w*w0 + y1.w*w1);
}

// ---------------------------------------------------------------------------
// Fused stage-2 combine + residual + LayerNorm + MLP (r2-refcheck-proven).
// One WAVE per row; lane == head (e0 = lane*8 spans exactly head `lane`).
// ---------------------------------------------------------------------------
__global__ __launch_bounds__(256) void ln_mlp_kernel(
    const float* __restrict__ x,
    const float* __restrict__ PA, const float* __restrict__ PM,
    const float* __restrict__ g, const float* __restrict__ beta,
    const float* __restrict__ w1, const float* __restrict__ b1,
    const float* __restrict__ w2, const float* __restrict__ b2,
    float* __restrict__ out)
{
    const int t = threadIdx.x;
    const int lane = t & 63;
    const int row = blockIdx.x * 4 + (t >> 6);
    const int b = row >> 9, q = row & 511;
    const long base = (long)row * D_MODEL;
    const int e0 = lane * 8;

    const long p0 = (((long)b * HEAD + lane) * 2 + 0) * SEQ + q;
    const long p1 = (((long)b * HEAD + lane) * 2 + 1) * SEQ + q;
    const float2 ml0 = *(const float2*)(PM + p0 * 2);
    const float2 ml1 = *(const float2*)(PM + p1 * 2);
    const float M = fmaxf(ml0.x, ml1.x);
    float cw0 = __builtin_amdgcn_exp2f(ml0.x - M);
    float cw1 = __builtin_amdgcn_exp2f(ml1.x - M);
    const float inv = 1.0f / fmaf(ml0.y, cw0, ml1.y * cw1);
    cw0 *= inv; cw1 *= inv;
    const float4 fa0 = *(const float4*)(PA + p0 * 8);
    const float4 fa1 = *(const float4*)(PA + p0 * 8 + 4);
    const float4 fb0 = *(const float4*)(PA + p1 * 8);
    const float4 fb1 = *(const float4*)(PA + p1 * 8 + 4);

    const float4 xa = *(const float4*)(x + base + e0);
    const float4 xb = *(const float4*)(x + base + e0 + 4);
    float z[8] = {
        xa.x + fa0.x * cw0 + fb0.x * cw1, xa.y + fa0.y * cw0 + fb0.y * cw1,
        xa.z + fa0.z * cw0 + fb0.z * cw1, xa.w + fa0.w * cw0 + fb0.w * cw1,
        xb.x + fa1.x * cw0 + fb1.x * cw1, xb.y + fa1.y * cw0 + fb1.y * cw1,
        xb.z + fa1.z * cw0 + fb1.z * cw1, xb.w + fa1.w * cw0 + fb1.w * cw1};

    float sum = 0.f;
#pragma unroll
    for (int j = 0; j < 8; ++j) sum += z[j];
#pragma unroll
    for (int o = 32; o > 0; o >>= 1) sum += __shfl_xor(sum, o);
    const float mu = sum * (1.0f / 512.0f);

    float d[8], ss = 0.f;
#pragma unroll
    for (int j = 0; j < 8; ++j) { d[j] = z[j] - mu; ss += d[j] * d[j]; }
#pragma unroll
    for (int o = 32; o > 0; o >>= 1) ss += __shfl_xor(ss, o);
    const float rs = rsqrtf(ss * (1.0f / 512.0f) + 1e-5f);

    const float4 ga = *(const float4*)(g + e0);
    const float4 gb = *(const float4*)(g + e0 + 4);
    const float4 ba = *(const float4*)(beta + e0);
    const float4 bb = *(const float4*)(beta + e0 + 4);
    const float gg[8] = {ga.x, ga.y, ga.z, ga.w, gb.x, gb.y, gb.z, gb.w};
    const float bt[8] = {ba.x, ba.y, ba.z, ba.w, bb.x, bb.y, bb.z, bb.w};
    float y[8];
#pragma unroll
    for (int j = 0; j < 8; ++j) y[j] = d[j] * rs * gg[j] + bt[j];

    float part[HIDD];
#pragma unroll
    for (int i = 0; i < HIDD; ++i) {
        const float4 wa = *(const float4*)(w1 + i * 512 + e0);
        const float4 wb = *(const float4*)(w1 + i * 512 + e0 + 4);
        part[i] = y[0] * wa.x + y[1] * wa.y + y[2] * wa.z + y[3] * wa.w
                + y[4] * wb.x + y[5] * wb.y + y[6] * wb.z + y[7] * wb.w;
    }
#pragma unroll
    for (int i = 0; i < HIDD; ++i)
#pragma unroll
        for (int o = 32; o > 0; o >>= 1) part[i] += __shfl_xor(part[i], o);

    float hv[HIDD];
#pragma unroll
    for (int i = 0; i < HIDD; ++i) hv[i] = fmaxf(part[i] + b1[i], 0.f);

    const float4 b2a = *(const float4*)(b2 + e0);
    const float4 b2b = *(const float4*)(b2 + e0 + 4);
    float o8[8] = {b2a.x, b2a.y, b2a.z, b2a.w, b2b.x, b2b.y, b2b.z, b2b.w};
#pragma unroll
    for (int j = 0; j < 8; ++j) {
        const float* wr = w2 + (long)(e0 + j) * 10;
        const float2 wA = *(const float2*)(wr);
        const float2 wB = *(const float2*)(wr + 2);
        const float2 wC = *(const float2*)(wr + 4);
        const float2 wD = *(const float2*)(wr + 6);
        const float2 wE = *(const float2*)(wr + 8);
        o8[j] += hv[0] * wA.x + hv[1] * wA.y + hv[2] * wB.x + hv[3] * wB.y
               + hv[4] * wC.x + hv[5] * wC.y + hv[6] * wD.x + hv[7] * wD.y
               + hv[8] * wE.x + hv[9] * wE.y;
    }

    *(float4*)(out + base + e0)     = make_float4(o8[0], o8[1], o8[2], o8[3]);
    *(float4*)(out + base + e0 + 4) = make_float4(o8[4], o8[5], o8[6], o8[7]);
}

extern "C" void kernel_launch(void* const* d_in, const int* in_sizes, int n_in,
                              void* d_out, int out_size, void* d_ws, size_t ws_size,
                              hipStream_t stream) {
    (void)in_sizes; (void)n_in; (void)out_size; (void)ws_size;
    const float* x    = (const float*)d_in[0];
    const float* xenc = (const float*)d_in[1];
    const float* Wq   = (const float*)d_in[2];
    const float* Wk   = (const float*)d_in[3];
    const float* Wv   = (const float*)d_in[4];
    const float* ln_g = (const float*)d_in[5];
    const float* ln_b = (const float*)d_in[6];
    const float* w1   = (const float*)d_in[7];
    const float* b1   = (const float*)d_in[8];
    const float* w2   = (const float*)d_in[9];
    const float* b2   = (const float*)d_in[10];
    float* out = (float*)d_out;

    // Workspace: EXACTLY 12M floats = 48 MiB. Liveness-verified aliasing:
    //   proj1:   w Q1[0,1) K1[1,2) V1[2,4) Kc[4,5) Vc[5,7)
    //   attn1:   r Q1,K1,V1            w PA[7,11) PM[11,12)
    //   combine: r PA,PM               w A[0,2)   (Q1,K1 dead)
    //   proj2:   r A                   w Qa[2,3) Qb[3,4)  (V1 dead)
    //   attn2:   r Qa,Qb,Kc,Vc         w PA[7,11) PM[11,12) (stage-1 dead)
    //   ln_mlp:  r x,PA,PM             w out
    float* ws = (float*)d_ws;
    float* Q1 = ws;                    // [ 0M, 1M)
    float* K1 = ws +  1048576;         // [ 1M, 2M)
    float* V1 = ws +  2097152;         // [ 2M, 4M)
    float* Kc = ws +  4194304;         // [ 4M, 5M)
    float* Vc = ws +  5242880;         // [ 5M, 7M)
    float* PA = ws +  7340032;         // [ 7M,11M)
    float* PM = ws + 11534336;         // [11M,12M)
    float* A  = ws;                    // [ 0M, 2M)
    float* Qa = ws +  2097152;         // [ 2M, 3M)
    float* Qb = ws +  3145728;         // [ 3M, 4M)

    proj_kernel<<<dim3(896), 256, 0, stream>>>(x, xenc, Wq, Wk, Wv,
                                               Q1, K1, V1, Kc, Vc);
    attn_kernel<<<dim3(BATCH * HEAD * 2), 128, 0, stream>>>(
        Q1, nullptr, K1, V1, PA, PM, 1);
    combine_kernel<<<dim3(1024), 256, 0, stream>>>(PA, PM, A);
    proj2_kernel<<<dim3(1024), 256, 0, stream>>>(A, Wq, Qa, Qb);
    attn_kernel<<<dim3(BATCH * HEAD * 2), 128, 0, stream>>>(
        Qa, Qb, Kc, Vc, PA, PM, 0);
    ln_mlp_kernel<<<dim3(1024), 256, 0, stream>>>(x, PA, PM, ln_g, ln_b,
                                                  w1, b1, w2, b2, out);
}